// Round 14
// baseline (86.379 us; speedup 1.0000x reference)
//
#include <hip/hip_runtime.h>
#include <hip/hip_bf16.h>
#include <stdint.h>

#define IN_DIM   4096
#define OUT_DIM  4096
#define RANK     256
#define MROWS    512      // 4*128 flattened batch rows
#define NNZ_CNT  262144
#define NBANK    4        // cursor banks (atomic-contention fix)
#define BCAP4    48       // per-(o,bank) capacity: mean 16, +8 sigma
#define ROWCAP   (NBANK * BCAP4)   // 192 entries per o-row

typedef __attribute__((ext_vector_type(8))) short bf16x8;
typedef __attribute__((ext_vector_type(4))) float f32x4;

// ---------------- workspace layout (bytes) ----------------
// Vhb bf16 [RANK][IN]     2 MiB  (Vh gathered, row-major = B^T for GEMM1)
// Usb bf16 [OUT][RANK]    2 MiB  (U*S gathered, row-major = B^T for GEMM2)
// xT  bf16 [IN][MROWS]    4 MiB  (x transposed, sparse path)
// t   f32  [MROWS][RANK]  512 KiB (gemm1 atomic accumulator, zeroed in prep)
// cur i32 [OUT*NBANK]     64 KiB  (banked bucket cursors, zeroed in prep)
// kvb int2 [OUT][NBANK][BCAP4] 6.3 MiB (banked {col, val-bits} buckets)
#define WS_VHB  ((size_t)0)
#define WS_USB  (WS_VHB + (size_t)RANK * IN_DIM * 2)
#define WS_XT   (WS_USB + (size_t)OUT_DIM * RANK * 2)
#define WS_T    (WS_XT  + (size_t)IN_DIM * MROWS * 2)
#define WS_CUR  (WS_T   + (size_t)MROWS * RANK * 4)
#define WS_KVB  (WS_CUR + (size_t)OUT_DIM * NBANK * 4)

__device__ inline uint4 pack8(float4 a, float4 b) {
    union { __hip_bfloat16 h[8]; uint4 u; } w;
    w.h[0] = __float2bfloat16(a.x); w.h[1] = __float2bfloat16(a.y);
    w.h[2] = __float2bfloat16(a.z); w.h[3] = __float2bfloat16(a.w);
    w.h[4] = __float2bfloat16(b.x); w.h[5] = __float2bfloat16(b.y);
    w.h[6] = __float2bfloat16(b.z); w.h[7] = __float2bfloat16(b.w);
    return w.u;
}

__device__ inline float bfbits(uint32_t lo16) {
    union { uint32_t u; float f; } w; w.u = lo16 << 16; return w.f;
}

__device__ inline void fma8(float* acc, uint4 u, float v) {
    acc[0] += v * bfbits(u.x & 0xffffu);
    acc[1] += v * bfbits(u.x >> 16);
    acc[2] += v * bfbits(u.y & 0xffffu);
    acc[3] += v * bfbits(u.y >> 16);
    acc[4] += v * bfbits(u.z & 0xffffu);
    acc[5] += v * bfbits(u.z >> 16);
    acc[6] += v * bfbits(u.w & 0xffffu);
    acc[7] += v * bfbits(u.w >> 16);
}

// ---------------------------------------------------------------------------
// prep: sections by bid
//   [0,512)     x -> xT : 64x64 tile transpose, float4 reads / uint2 stores;
//               each block also zeroes 256 floats of t
//   [512,768)   Vhb gather (512 subvecs/block, 2/thread)
//   [768,1024)  Usb gather (*S); first 64 blocks also zero banked cursors
// ---------------------------------------------------------------------------
__global__ __launch_bounds__(256) void prep_kernel(
    const float* __restrict__ x,
    const int*   __restrict__ uidx, const float* __restrict__ ucode,
    const float* __restrict__ S,
    const int*   __restrict__ vidx, const float* __restrict__ vcode,
    __hip_bfloat16* __restrict__ Vhb, __hip_bfloat16* __restrict__ Usb,
    __hip_bfloat16* __restrict__ xT,
    int* __restrict__ cursor, float* __restrict__ tbuf)
{
    const int bid = blockIdx.x;
    const int t   = threadIdx.x;

    if (bid < 512) {
        __shared__ float tile[64][65];
        const int i0 = (bid >> 3) * 64;      // 64 i-tiles
        const int m0 = (bid & 7) * 64;       // 8 m-tiles
        const int rr = t >> 4, c4 = t & 15;
        #pragma unroll
        for (int p = 0; p < 4; p++) {
            int r = p * 16 + rr;
            float4 v = *(const float4*)(x + (size_t)(m0 + r) * IN_DIM + i0 + c4 * 4);
            tile[r][c4 * 4 + 0] = v.x;
            tile[r][c4 * 4 + 1] = v.y;
            tile[r][c4 * 4 + 2] = v.z;
            tile[r][c4 * 4 + 3] = v.w;
        }
        tbuf[bid * 256 + t] = 0.f;           // zero t (512*256 = |t|)
        __syncthreads();
        #pragma unroll
        for (int p = 0; p < 4; p++) {
            int i = p * 16 + rr;
            union { __hip_bfloat16 h[4]; uint2 u; } w;
            w.h[0] = __float2bfloat16(tile[c4 * 4 + 0][i]);
            w.h[1] = __float2bfloat16(tile[c4 * 4 + 1][i]);
            w.h[2] = __float2bfloat16(tile[c4 * 4 + 2][i]);
            w.h[3] = __float2bfloat16(tile[c4 * 4 + 3][i]);
            *(uint2*)(xT + (size_t)(i0 + i) * MROWS + m0 + c4 * 4) = w.u;
        }
    } else if (bid < 768) {
        int base = (bid - 512) * 512;
        #pragma unroll
        for (int q = 0; q < 2; q++) {
            int sv = base + q * 256 + t;
            int cb = vidx[sv];
            const float4* vc = (const float4*)(vcode + (size_t)cb * 8);
            *(uint4*)(Vhb + (size_t)sv * 8) = pack8(vc[0], vc[1]);
        }
    } else {
        int base = (bid - 768) * 512;
        #pragma unroll
        for (int q = 0; q < 2; q++) {
            int sv = base + q * 256 + t;
            int cb = uidx[sv];
            int r0 = (sv & 31) * 8;
            const float4* uc = (const float4*)(ucode + (size_t)cb * 8);
            const float4* sp = (const float4*)(S + r0);
            float4 a = uc[0], b = uc[1], sa = sp[0], sb = sp[1];
            a.x *= sa.x; a.y *= sa.y; a.z *= sa.z; a.w *= sa.w;
            b.x *= sb.x; b.y *= sb.y; b.z *= sb.z; b.w *= sb.w;
            *(uint4*)(Usb + (size_t)sv * 8) = pack8(a, b);
        }
        if (bid < 832) cursor[(bid - 768) * 256 + t] = 0;   // 64*256 = 16384
    }
}

// ---------------------------------------------------------------------------
// scatter + gemm1 fused (both depend only on prep; independent outputs).
//   blocks [0,1024):    scatter residuals into banked per-row buckets.
//     bank = k & 3 -> cursor lines carry 256 serialized increments instead of
//     1024 (atomic-serialization fix; R12 showed volume isn't the cost).
//   blocks [1024,1280): gemm1 MFMA, split-K=8, atomicAdd into t.
// ---------------------------------------------------------------------------
__global__ __launch_bounds__(256) void scatter_gemm1_kernel(
    const int* __restrict__ ridx, const float* __restrict__ rval,
    int* __restrict__ cursor, int2* __restrict__ kvb,
    const float* __restrict__ x,
    const __hip_bfloat16* __restrict__ Vhb,
    float* __restrict__ tbuf)
{
    if (blockIdx.x < 1024) {
        int k = blockIdx.x * 256 + threadIdx.x;
        int idx = ridx[k];
        int o = idx >> 12, i = idx & 4095;
        int bank = k & (NBANK - 1);
        int pos = atomicAdd(&cursor[o * NBANK + bank], 1);
        if (pos < BCAP4)                   // overflow ~1e-6 for fixed input
            kvb[(size_t)o * ROWCAP + bank * BCAP4 + pos] =
                make_int2(i, __float_as_int(rval[k]));
        return;
    }

    // ---- gemm1: t[512,256] += bf16(x) @ Vhb^T. split-K=8, BK=64, 8 steps ----
    __shared__ __align__(16) __hip_bfloat16 As[64][72];   // pitch 72: 2-way banks
    __shared__ __align__(16) __hip_bfloat16 Bs[64][72];

    const int bid = blockIdx.x - 1024;           // [0,256)
    const int ks = bid & 7, nb = (bid >> 3) & 3, mb = bid >> 5;
    const int m0 = mb * 64, n0 = nb * 64, kbase = ks * 512;
    const int t = threadIdx.x;
    const int lane = t & 63, wave = t >> 6;
    const int wm = wave >> 1, wn = wave & 1;
    const int l15 = lane & 15, l4 = lane >> 4;
    const int srow = t >> 2, sg = t & 3;

    f32x4 acc[2][2];
    #pragma unroll
    for (int i = 0; i < 2; i++)
        #pragma unroll
        for (int j = 0; j < 2; j++) acc[i][j] = (f32x4){0.f, 0.f, 0.f, 0.f};

    for (int s = 0; s < 8; s++) {
        int k0 = kbase + s * 64;
        const float* xp = x + (size_t)(m0 + srow) * IN_DIM + k0 + sg * 16;
        *(uint4*)&As[srow][sg * 16] =
            pack8(*(const float4*)xp, *(const float4*)(xp + 4));
        *(uint4*)&As[srow][sg * 16 + 8] =
            pack8(*(const float4*)(xp + 8), *(const float4*)(xp + 12));
        const __hip_bfloat16* bp = Vhb + (size_t)(n0 + srow) * IN_DIM + k0 + sg * 16;
        *(uint4*)&Bs[srow][sg * 16]     = *(const uint4*)bp;
        *(uint4*)&Bs[srow][sg * 16 + 8] = *(const uint4*)(bp + 8);
        __syncthreads();
        #pragma unroll
        for (int kk = 0; kk < 2; kk++) {
            bf16x8 a[2], b[2];
            #pragma unroll
            for (int i = 0; i < 2; i++)
                a[i] = *(const bf16x8*)&As[wm * 32 + i * 16 + l15][kk * 32 + l4 * 8];
            #pragma unroll
            for (int j = 0; j < 2; j++)
                b[j] = *(const bf16x8*)&Bs[wn * 32 + j * 16 + l15][kk * 32 + l4 * 8];
            #pragma unroll
            for (int i = 0; i < 2; i++)
                #pragma unroll
                for (int j = 0; j < 2; j++)
                    acc[i][j] = __builtin_amdgcn_mfma_f32_16x16x32_bf16(
                        a[i], b[j], acc[i][j], 0, 0, 0);
        }
        __syncthreads();
    }

    #pragma unroll
    for (int i = 0; i < 2; i++)
        #pragma unroll
        for (int j = 0; j < 2; j++)
            #pragma unroll
            for (int q = 0; q < 4; q++) {
                int row = m0 + wm * 32 + i * 16 + l4 * 4 + q;
                int col = n0 + wn * 32 + j * 16 + l15;
                atomicAdd(&tbuf[row * RANK + col], acc[i][j][q]);
            }
}

// ---------------------------------------------------------------------------
// GEMM2 + sparse fused: out[m][o] = (t @ Usb^T)[m][o] + residual[m][o].
// 32m x 64o tiles, grid 1024, XCD-affinity swizzle (mb = bid & 15) -> xT
// working set 512 KB/XCD, L2-resident (R13: -10us confirmed).
// Phase B iterates 4 bank-segments interleaved: 4 independent exec-masked
// load chains per k-iteration preserve MLP.
// ---------------------------------------------------------------------------
__global__ __launch_bounds__(256) void gemm2_sparse_kernel(
    const float* __restrict__ tbuf,
    const __hip_bfloat16* __restrict__ Usb,
    const int* __restrict__ cursor,
    const int2* __restrict__ kvb,
    const __hip_bfloat16* __restrict__ xT,
    float* __restrict__ out)
{
    __shared__ __align__(16) char smem[14080];
    typedef __hip_bfloat16 bfrowA[72];
    typedef __hip_bfloat16 bfrowB[72];
    bfrowA* As = (bfrowA*)smem;                    //  32x72x2 = 4608 B
    bfrowB* Bs = (bfrowB*)(smem + 4608);           //  64x72x2 = 9216 B
    float (*sacc)[33] = (float(*)[33])smem;        //  64x33x4 = 8448 B (reused)

    const int bid = blockIdx.x;
    const int mb = bid & 15, nb = bid >> 4;        // XCD-affinity mapping
    const int m0 = mb * 32, n0 = nb * 64;
    const int t = threadIdx.x;
    const int lane = t & 63, wave = t >> 6;
    const int wm = wave >> 1, wn = wave & 1;
    const int l15 = lane & 15, l4 = lane >> 4;

    f32x4 acc[2];
    acc[0] = (f32x4){0.f, 0.f, 0.f, 0.f};
    acc[1] = (f32x4){0.f, 0.f, 0.f, 0.f};

    // ---- Phase A: dense MFMA ----
    {
        const int sa_row = t >> 3, sa_g = t & 7;   // A: 32 rows x 8 chunks of 8
        const int sb_row = t >> 2, sb_g = t & 3;   // B: 64 rows x 4 chunks of 16
        for (int s = 0; s < 4; s++) {
            int k0 = s * 64;
            const float* tp = tbuf + (size_t)(m0 + sa_row) * RANK + k0 + sa_g * 8;
            *(uint4*)&As[sa_row][sa_g * 8] =
                pack8(*(const float4*)tp, *(const float4*)(tp + 4));
            const __hip_bfloat16* bp =
                Usb + (size_t)(n0 + sb_row) * RANK + k0 + sb_g * 16;
            *(uint4*)&Bs[sb_row][sb_g * 16]     = *(const uint4*)bp;
            *(uint4*)&Bs[sb_row][sb_g * 16 + 8] = *(const uint4*)(bp + 8);
            __syncthreads();
            #pragma unroll
            for (int kk = 0; kk < 2; kk++) {
                bf16x8 a, b[2];
                a = *(const bf16x8*)&As[wm * 16 + l15][kk * 32 + l4 * 8];
                #pragma unroll
                for (int j = 0; j < 2; j++)
                    b[j] = *(const bf16x8*)&Bs[wn * 32 + j * 16 + l15][kk * 32 + l4 * 8];
                #pragma unroll
                for (int j = 0; j < 2; j++)
                    acc[j] = __builtin_amdgcn_mfma_f32_16x16x32_bf16(
                        a, b[j], acc[j], 0, 0, 0);
            }
            __syncthreads();
        }
    }

    // ---- Phase B: residual into sacc (4 bank-streams interleaved) ----
    {
        const int orel = t >> 2;              // o-row within tile (64)
        const int ms   = t & 3;               // 8-m slice (32m / 4)
        const int o    = n0 + orel;
        int c0 = cursor[o * NBANK + 0]; c0 = c0 < BCAP4 ? c0 : BCAP4;
        int c1 = cursor[o * NBANK + 1]; c1 = c1 < BCAP4 ? c1 : BCAP4;
        int c2 = cursor[o * NBANK + 2]; c2 = c2 < BCAP4 ? c2 : BCAP4;
        int c3 = cursor[o * NBANK + 3]; c3 = c3 < BCAP4 ? c3 : BCAP4;
        int mx = max(max(c0, c1), max(c2, c3));
        const int2* kp = kvb + (size_t)o * ROWCAP;
        const __hip_bfloat16* xm = xT + m0 + ms * 8;

        float r[8];
        #pragma unroll
        for (int j = 0; j < 8; j++) r[j] = 0.f;

        for (int k = 0; k < mx; k++) {
            if (k < c0) {
                int2 e = kp[k];
                uint4 u = *(const uint4*)(xm + (size_t)e.x * MROWS);
                fma8(r, u, __int_as_float(e.y));
            }
            if (k < c1) {
                int2 e = kp[BCAP4 + k];
                uint4 u = *(const uint4*)(xm + (size_t)e.x * MROWS);
                fma8(r, u, __int_as_float(e.y));
            }
            if (k < c2) {
                int2 e = kp[2 * BCAP4 + k];
                uint4 u = *(const uint4*)(xm + (size_t)e.x * MROWS);
                fma8(r, u, __int_as_float(e.y));
            }
            if (k < c3) {
                int2 e = kp[3 * BCAP4 + k];
                uint4 u = *(const uint4*)(xm + (size_t)e.x * MROWS);
                fma8(r, u, __int_as_float(e.y));
            }
        }

        *(float4*)&sacc[orel][ms * 8]     = make_float4(r[0], r[1], r[2], r[3]);
        *(float4*)&sacc[orel][ms * 8 + 4] = make_float4(r[4], r[5], r[6], r[7]);
    }
    __syncthreads();

    // ---- Phase C: epilogue (dense + sparse, single write) ----
    #pragma unroll
    for (int j = 0; j < 2; j++)
        #pragma unroll
        for (int q = 0; q < 4; q++) {
            int rrel = wm * 16 + l4 * 4 + q;        // m within tile (32)
            int crel = wn * 32 + j * 16 + l15;      // o within tile (64)
            out[(size_t)(m0 + rrel) * OUT_DIM + n0 + crel] =
                acc[j][q] + sacc[crel][rrel];
        }
}

// ---------------------------------------------------------------------------
extern "C" void kernel_launch(void* const* d_in, const int* in_sizes, int n_in,
                              void* d_out, int out_size, void* d_ws, size_t ws_size,
                              hipStream_t stream)
{
    const float* x    = (const float*)d_in[0];
    const int*   uidx = (const int*)  d_in[1];
    const float* ucb  = (const float*)d_in[2];
    const float* S    = (const float*)d_in[3];
    const int*   vidx = (const int*)  d_in[4];
    const float* vcb  = (const float*)d_in[5];
    const int*   ridx = (const int*)  d_in[6];
    const float* rval = (const float*)d_in[7];
    float* out = (float*)d_out;

    char* ws = (char*)d_ws;
    __hip_bfloat16* Vhb  = (__hip_bfloat16*)(ws + WS_VHB);
    __hip_bfloat16* Usb  = (__hip_bfloat16*)(ws + WS_USB);
    __hip_bfloat16* xT   = (__hip_bfloat16*)(ws + WS_XT);
    float*          tbuf = (float*)(ws + WS_T);
    int*            cur  = (int*)(ws + WS_CUR);
    int2*           kvb  = (int2*)(ws + WS_KVB);

    prep_kernel<<<dim3(1024), dim3(256), 0, stream>>>(
        x, uidx, ucb, S, vidx, vcb, Vhb, Usb, xT, cur, tbuf);

    scatter_gemm1_kernel<<<dim3(1280), dim3(256), 0, stream>>>(
        ridx, rval, cur, kvb, x, Vhb, tbuf);

    gemm2_sparse_kernel<<<dim3(1024), dim3(256), 0, stream>>>(
        tbuf, Usb, cur, kvb, xT, out);
}

// Round 15
// 78.447 us; speedup vs baseline: 1.1011x; 1.1011x over previous
//
#include <hip/hip_runtime.h>
#include <hip/hip_bf16.h>
#include <stdint.h>

#define IN_DIM   4096
#define OUT_DIM  4096
#define RANK     256
#define MROWS    512      // 4*128 flattened batch rows
#define NNZ_CNT  262144
#define NBANK    4        // cursor banks (atomic-serialization fix, R14: -12us)
#define BCAP4    48       // per-(o,bank) capacity: mean 16, +8 sigma
#define ROWCAP   (NBANK * BCAP4)   // 192 entries per o-row

typedef __attribute__((ext_vector_type(8))) short bf16x8;
typedef __attribute__((ext_vector_type(4))) float f32x4;

// ---------------- workspace layout (bytes) ----------------
// Vhb bf16 [RANK][IN]     2 MiB  (Vh gathered, row-major = B^T for GEMM1)
// Usb bf16 [OUT][RANK]    2 MiB  (U*S gathered, row-major = B^T for GEMM2)
// xT  bf16 [IN][MROWS]    4 MiB  (x transposed, sparse path)
// t   f32  [MROWS][RANK]  512 KiB (gemm1 atomic accumulator, zeroed in prep)
// cur i32 [OUT*NBANK]     64 KiB  (banked bucket cursors, zeroed in prep)
// kvb int2 [OUT][NBANK][BCAP4] 6.3 MiB (banked {col, val-bits} buckets)
#define WS_VHB  ((size_t)0)
#define WS_USB  (WS_VHB + (size_t)RANK * IN_DIM * 2)
#define WS_XT   (WS_USB + (size_t)OUT_DIM * RANK * 2)
#define WS_T    (WS_XT  + (size_t)IN_DIM * MROWS * 2)
#define WS_CUR  (WS_T   + (size_t)MROWS * RANK * 4)
#define WS_KVB  (WS_CUR + (size_t)OUT_DIM * NBANK * 4)

__device__ inline uint4 pack8(float4 a, float4 b) {
    union { __hip_bfloat16 h[8]; uint4 u; } w;
    w.h[0] = __float2bfloat16(a.x); w.h[1] = __float2bfloat16(a.y);
    w.h[2] = __float2bfloat16(a.z); w.h[3] = __float2bfloat16(a.w);
    w.h[4] = __float2bfloat16(b.x); w.h[5] = __float2bfloat16(b.y);
    w.h[6] = __float2bfloat16(b.z); w.h[7] = __float2bfloat16(b.w);
    return w.u;
}

__device__ inline float bfbits(uint32_t lo16) {
    union { uint32_t u; float f; } w; w.u = lo16 << 16; return w.f;
}

__device__ inline void fma8(float* acc, uint4 u, float v) {
    acc[0] += v * bfbits(u.x & 0xffffu);
    acc[1] += v * bfbits(u.x >> 16);
    acc[2] += v * bfbits(u.y & 0xffffu);
    acc[3] += v * bfbits(u.y >> 16);
    acc[4] += v * bfbits(u.z & 0xffffu);
    acc[5] += v * bfbits(u.z >> 16);
    acc[6] += v * bfbits(u.w & 0xffffu);
    acc[7] += v * bfbits(u.w >> 16);
}

// ---------------------------------------------------------------------------
// prep: sections by bid
//   [0,512)     x -> xT : 64x64 tile transpose, float4 reads / uint2 stores;
//               each block also zeroes 256 floats of t
//   [512,768)   Vhb gather (512 subvecs/block, 2/thread)
//   [768,1024)  Usb gather (*S); first 64 blocks also zero banked cursors
// ---------------------------------------------------------------------------
__global__ __launch_bounds__(256) void prep_kernel(
    const float* __restrict__ x,
    const int*   __restrict__ uidx, const float* __restrict__ ucode,
    const float* __restrict__ S,
    const int*   __restrict__ vidx, const float* __restrict__ vcode,
    __hip_bfloat16* __restrict__ Vhb, __hip_bfloat16* __restrict__ Usb,
    __hip_bfloat16* __restrict__ xT,
    int* __restrict__ cursor, float* __restrict__ tbuf)
{
    const int bid = blockIdx.x;
    const int t   = threadIdx.x;

    if (bid < 512) {
        __shared__ float tile[64][65];
        const int i0 = (bid >> 3) * 64;      // 64 i-tiles
        const int m0 = (bid & 7) * 64;       // 8 m-tiles
        const int rr = t >> 4, c4 = t & 15;
        #pragma unroll
        for (int p = 0; p < 4; p++) {
            int r = p * 16 + rr;
            float4 v = *(const float4*)(x + (size_t)(m0 + r) * IN_DIM + i0 + c4 * 4);
            tile[r][c4 * 4 + 0] = v.x;
            tile[r][c4 * 4 + 1] = v.y;
            tile[r][c4 * 4 + 2] = v.z;
            tile[r][c4 * 4 + 3] = v.w;
        }
        tbuf[bid * 256 + t] = 0.f;           // zero t (512*256 = |t|)
        __syncthreads();
        #pragma unroll
        for (int p = 0; p < 4; p++) {
            int i = p * 16 + rr;
            union { __hip_bfloat16 h[4]; uint2 u; } w;
            w.h[0] = __float2bfloat16(tile[c4 * 4 + 0][i]);
            w.h[1] = __float2bfloat16(tile[c4 * 4 + 1][i]);
            w.h[2] = __float2bfloat16(tile[c4 * 4 + 2][i]);
            w.h[3] = __float2bfloat16(tile[c4 * 4 + 3][i]);
            *(uint2*)(xT + (size_t)(i0 + i) * MROWS + m0 + c4 * 4) = w.u;
        }
    } else if (bid < 768) {
        int base = (bid - 512) * 512;
        #pragma unroll
        for (int q = 0; q < 2; q++) {
            int sv = base + q * 256 + t;
            int cb = vidx[sv];
            const float4* vc = (const float4*)(vcode + (size_t)cb * 8);
            *(uint4*)(Vhb + (size_t)sv * 8) = pack8(vc[0], vc[1]);
        }
    } else {
        int base = (bid - 768) * 512;
        #pragma unroll
        for (int q = 0; q < 2; q++) {
            int sv = base + q * 256 + t;
            int cb = uidx[sv];
            int r0 = (sv & 31) * 8;
            const float4* uc = (const float4*)(ucode + (size_t)cb * 8);
            const float4* sp = (const float4*)(S + r0);
            float4 a = uc[0], b = uc[1], sa = sp[0], sb = sp[1];
            a.x *= sa.x; a.y *= sa.y; a.z *= sa.z; a.w *= sa.w;
            b.x *= sb.x; b.y *= sb.y; b.z *= sb.z; b.w *= sb.w;
            *(uint4*)(Usb + (size_t)sv * 8) = pack8(a, b);
        }
        if (bid < 832) cursor[(bid - 768) * 256 + t] = 0;   // 64*256 = 16384
    }
}

// ---------------------------------------------------------------------------
// scatter + gemm1 fused (both depend only on prep; independent outputs).
//   blocks [0,1024):    scatter residuals into banked per-row buckets
//                       (bank = k & 3 -> 256 serialized increments per line)
//   blocks [1024,1280): gemm1 MFMA, split-K=8, atomicAdd into t.
// ---------------------------------------------------------------------------
__global__ __launch_bounds__(256) void scatter_gemm1_kernel(
    const int* __restrict__ ridx, const float* __restrict__ rval,
    int* __restrict__ cursor, int2* __restrict__ kvb,
    const float* __restrict__ x,
    const __hip_bfloat16* __restrict__ Vhb,
    float* __restrict__ tbuf)
{
    if (blockIdx.x < 1024) {
        int k = blockIdx.x * 256 + threadIdx.x;
        int idx = ridx[k];
        int o = idx >> 12, i = idx & 4095;
        int bank = k & (NBANK - 1);
        int pos = atomicAdd(&cursor[o * NBANK + bank], 1);
        if (pos < BCAP4)                   // overflow ~1e-6 for fixed input
            kvb[(size_t)o * ROWCAP + bank * BCAP4 + pos] =
                make_int2(i, __float_as_int(rval[k]));
        return;
    }

    // ---- gemm1: t[512,256] += bf16(x) @ Vhb^T. split-K=8, BK=64, 8 steps ----
    __shared__ __align__(16) __hip_bfloat16 As[64][72];   // pitch 72: 2-way banks
    __shared__ __align__(16) __hip_bfloat16 Bs[64][72];

    const int bid = blockIdx.x - 1024;           // [0,256)
    const int ks = bid & 7, nb = (bid >> 3) & 3, mb = bid >> 5;
    const int m0 = mb * 64, n0 = nb * 64, kbase = ks * 512;
    const int t = threadIdx.x;
    const int lane = t & 63, wave = t >> 6;
    const int wm = wave >> 1, wn = wave & 1;
    const int l15 = lane & 15, l4 = lane >> 4;
    const int srow = t >> 2, sg = t & 3;

    f32x4 acc[2][2];
    #pragma unroll
    for (int i = 0; i < 2; i++)
        #pragma unroll
        for (int j = 0; j < 2; j++) acc[i][j] = (f32x4){0.f, 0.f, 0.f, 0.f};

    for (int s = 0; s < 8; s++) {
        int k0 = kbase + s * 64;
        const float* xp = x + (size_t)(m0 + srow) * IN_DIM + k0 + sg * 16;
        *(uint4*)&As[srow][sg * 16] =
            pack8(*(const float4*)xp, *(const float4*)(xp + 4));
        *(uint4*)&As[srow][sg * 16 + 8] =
            pack8(*(const float4*)(xp + 8), *(const float4*)(xp + 12));
        const __hip_bfloat16* bp = Vhb + (size_t)(n0 + srow) * IN_DIM + k0 + sg * 16;
        *(uint4*)&Bs[srow][sg * 16]     = *(const uint4*)bp;
        *(uint4*)&Bs[srow][sg * 16 + 8] = *(const uint4*)(bp + 8);
        __syncthreads();
        #pragma unroll
        for (int kk = 0; kk < 2; kk++) {
            bf16x8 a[2], b[2];
            #pragma unroll
            for (int i = 0; i < 2; i++)
                a[i] = *(const bf16x8*)&As[wm * 32 + i * 16 + l15][kk * 32 + l4 * 8];
            #pragma unroll
            for (int j = 0; j < 2; j++)
                b[j] = *(const bf16x8*)&Bs[wn * 32 + j * 16 + l15][kk * 32 + l4 * 8];
            #pragma unroll
            for (int i = 0; i < 2; i++)
                #pragma unroll
                for (int j = 0; j < 2; j++)
                    acc[i][j] = __builtin_amdgcn_mfma_f32_16x16x32_bf16(
                        a[i], b[j], acc[i][j], 0, 0, 0);
        }
        __syncthreads();
    }

    #pragma unroll
    for (int i = 0; i < 2; i++)
        #pragma unroll
        for (int j = 0; j < 2; j++)
            #pragma unroll
            for (int q = 0; q < 4; q++) {
                int row = m0 + wm * 32 + i * 16 + l4 * 4 + q;
                int col = n0 + wn * 32 + j * 16 + l15;
                atomicAdd(&tbuf[row * RANK + col], acc[i][j][q]);
            }
}

// ---------------------------------------------------------------------------
// GEMM2 + sparse fused: out[m][o] = (t @ Usb^T)[m][o] + residual[m][o].
// 32m x 64o tiles, grid 1024, XCD-affinity swizzle (mb = bid & 15) -> xT
// L2-resident per XCD (R13: -10us confirmed).
// Phase B: per-bank segments processed with the R13-proven 8-deep unroll
// (8 entry loads up front -> 8 independent xT gathers in flight). R14's
// interleaved-bank loop halved MLP and doubled phase-B time — reverted.
// ---------------------------------------------------------------------------
__global__ __launch_bounds__(256) void gemm2_sparse_kernel(
    const float* __restrict__ tbuf,
    const __hip_bfloat16* __restrict__ Usb,
    const int* __restrict__ cursor,
    const int2* __restrict__ kvb,
    const __hip_bfloat16* __restrict__ xT,
    float* __restrict__ out)
{
    __shared__ __align__(16) char smem[14080];
    typedef __hip_bfloat16 bfrowA[72];
    typedef __hip_bfloat16 bfrowB[72];
    bfrowA* As = (bfrowA*)smem;                    //  32x72x2 = 4608 B
    bfrowB* Bs = (bfrowB*)(smem + 4608);           //  64x72x2 = 9216 B
    float (*sacc)[33] = (float(*)[33])smem;        //  64x33x4 = 8448 B (reused)

    const int bid = blockIdx.x;
    const int mb = bid & 15, nb = bid >> 4;        // XCD-affinity mapping
    const int m0 = mb * 32, n0 = nb * 64;
    const int t = threadIdx.x;
    const int lane = t & 63, wave = t >> 6;
    const int wm = wave >> 1, wn = wave & 1;
    const int l15 = lane & 15, l4 = lane >> 4;

    f32x4 acc[2];
    acc[0] = (f32x4){0.f, 0.f, 0.f, 0.f};
    acc[1] = (f32x4){0.f, 0.f, 0.f, 0.f};

    // ---- Phase A: dense MFMA ----
    {
        const int sa_row = t >> 3, sa_g = t & 7;   // A: 32 rows x 8 chunks of 8
        const int sb_row = t >> 2, sb_g = t & 3;   // B: 64 rows x 4 chunks of 16
        for (int s = 0; s < 4; s++) {
            int k0 = s * 64;
            const float* tp = tbuf + (size_t)(m0 + sa_row) * RANK + k0 + sa_g * 8;
            *(uint4*)&As[sa_row][sa_g * 8] =
                pack8(*(const float4*)tp, *(const float4*)(tp + 4));
            const __hip_bfloat16* bp =
                Usb + (size_t)(n0 + sb_row) * RANK + k0 + sb_g * 16;
            *(uint4*)&Bs[sb_row][sb_g * 16]     = *(const uint4*)bp;
            *(uint4*)&Bs[sb_row][sb_g * 16 + 8] = *(const uint4*)(bp + 8);
            __syncthreads();
            #pragma unroll
            for (int kk = 0; kk < 2; kk++) {
                bf16x8 a, b[2];
                a = *(const bf16x8*)&As[wm * 16 + l15][kk * 32 + l4 * 8];
                #pragma unroll
                for (int j = 0; j < 2; j++)
                    b[j] = *(const bf16x8*)&Bs[wn * 32 + j * 16 + l15][kk * 32 + l4 * 8];
                #pragma unroll
                for (int j = 0; j < 2; j++)
                    acc[j] = __builtin_amdgcn_mfma_f32_16x16x32_bf16(
                        a, b[j], acc[j], 0, 0, 0);
            }
            __syncthreads();
        }
    }

    // ---- Phase B: residual into sacc (per-bank 8-deep unroll, MLP=8) ----
    {
        const int orel = t >> 2;              // o-row within tile (64)
        const int ms   = t & 3;               // 8-m slice (32m / 4)
        const int o    = n0 + orel;
        int4 cq = *(const int4*)(cursor + o * NBANK);   // one 16B cursor read
        const int2* kp = kvb + (size_t)o * ROWCAP;
        const __hip_bfloat16* xm = xT + m0 + ms * 8;

        float r[8];
        #pragma unroll
        for (int j = 0; j < 8; j++) r[j] = 0.f;

        #pragma unroll
        for (int b = 0; b < NBANK; b++) {
            int cb = (b == 0) ? cq.x : (b == 1) ? cq.y : (b == 2) ? cq.z : cq.w;
            cb = cb < BCAP4 ? cb : BCAP4;
            const int2* seg = kp + b * BCAP4;
            int k = 0;
            for (; k + 8 <= cb; k += 8) {
                int2 e[8];
                #pragma unroll
                for (int j = 0; j < 8; j++) e[j] = seg[k + j];
                uint4 u[8];
                #pragma unroll
                for (int j = 0; j < 8; j++)
                    u[j] = *(const uint4*)(xm + (size_t)e[j].x * MROWS);
                #pragma unroll
                for (int j = 0; j < 8; j++)
                    fma8(r, u[j], __int_as_float(e[j].y));
            }
            // tail (cb mod 8, <=7 entries): 4-deep then scalar
            if (k + 4 <= cb) {
                int2 e[4];
                #pragma unroll
                for (int j = 0; j < 4; j++) e[j] = seg[k + j];
                uint4 u[4];
                #pragma unroll
                for (int j = 0; j < 4; j++)
                    u[j] = *(const uint4*)(xm + (size_t)e[j].x * MROWS);
                #pragma unroll
                for (int j = 0; j < 4; j++)
                    fma8(r, u[j], __int_as_float(e[j].y));
                k += 4;
            }
            for (; k < cb; k++) {
                int2 e = seg[k];
                uint4 u = *(const uint4*)(xm + (size_t)e.x * MROWS);
                fma8(r, u, __int_as_float(e.y));
            }
        }

        *(float4*)&sacc[orel][ms * 8]     = make_float4(r[0], r[1], r[2], r[3]);
        *(float4*)&sacc[orel][ms * 8 + 4] = make_float4(r[4], r[5], r[6], r[7]);
    }
    __syncthreads();

    // ---- Phase C: epilogue (dense + sparse, single write) ----
    #pragma unroll
    for (int j = 0; j < 2; j++)
        #pragma unroll
        for (int q = 0; q < 4; q++) {
            int rrel = wm * 16 + l4 * 4 + q;        // m within tile (32)
            int crel = wn * 32 + j * 16 + l15;      // o within tile (64)
            out[(size_t)(m0 + rrel) * OUT_DIM + n0 + crel] =
                acc[j][q] + sacc[crel][rrel];
        }
}

// ---------------------------------------------------------------------------
extern "C" void kernel_launch(void* const* d_in, const int* in_sizes, int n_in,
                              void* d_out, int out_size, void* d_ws, size_t ws_size,
                              hipStream_t stream)
{
    const float* x    = (const float*)d_in[0];
    const int*   uidx = (const int*)  d_in[1];
    const float* ucb  = (const float*)d_in[2];
    const float* S    = (const float*)d_in[3];
    const int*   vidx = (const int*)  d_in[4];
    const float* vcb  = (const float*)d_in[5];
    const int*   ridx = (const int*)  d_in[6];
    const float* rval = (const float*)d_in[7];
    float* out = (float*)d_out;

    char* ws = (char*)d_ws;
    __hip_bfloat16* Vhb  = (__hip_bfloat16*)(ws + WS_VHB);
    __hip_bfloat16* Usb  = (__hip_bfloat16*)(ws + WS_USB);
    __hip_bfloat16* xT   = (__hip_bfloat16*)(ws + WS_XT);
    float*          tbuf = (float*)(ws + WS_T);
    int*            cur  = (int*)(ws + WS_CUR);
    int2*           kvb  = (int2*)(ws + WS_KVB);

    prep_kernel<<<dim3(1024), dim3(256), 0, stream>>>(
        x, uidx, ucb, S, vidx, vcb, Vhb, Usb, xT, cur, tbuf);

    scatter_gemm1_kernel<<<dim3(1280), dim3(256), 0, stream>>>(
        ridx, rval, cur, kvb, x, Vhb, tbuf);

    gemm2_sparse_kernel<<<dim3(1024), dim3(256), 0, stream>>>(
        tbuf, Usb, cur, kvb, xT, out);
}

// Round 16
// 62.690 us; speedup vs baseline: 1.3779x; 1.2513x over previous
//
#include <hip/hip_runtime.h>
#include <hip/hip_bf16.h>
#include <stdint.h>

#define IN_DIM   4096
#define OUT_DIM  4096
#define RANK     256
#define MROWS    512      // 4*128 flattened batch rows
#define NNZ_CNT  262144
#define BCAP     128      // contiguous bucket capacity per row (mean 64, +8 sigma)
#define CSTRIDE  16       // cursor padded to one 64B line per row (contention fix)

typedef __attribute__((ext_vector_type(8))) short bf16x8;
typedef __attribute__((ext_vector_type(4))) float f32x4;

// ---------------- workspace layout (bytes) ----------------
// Vhb bf16 [RANK][IN]     2 MiB  (Vh gathered, row-major = B^T for GEMM1)
// Usb bf16 [OUT][RANK]    2 MiB  (U*S gathered, row-major = B^T for GEMM2)
// xT  bf16 [IN][MROWS]    4 MiB  (x transposed, sparse path)
// t   f32  [MROWS][RANK]  512 KiB (gemm1 atomic accumulator, zeroed in prep)
// cur i32 [OUT*CSTRIDE]   256 KiB (line-padded cursors: 64 atomics/line)
// kvb int2 [OUT][BCAP]    4 MiB  (contiguous {col, val-bits} buckets)
#define WS_VHB  ((size_t)0)
#define WS_USB  (WS_VHB + (size_t)RANK * IN_DIM * 2)
#define WS_XT   (WS_USB + (size_t)OUT_DIM * RANK * 2)
#define WS_T    (WS_XT  + (size_t)IN_DIM * MROWS * 2)
#define WS_CUR  (WS_T   + (size_t)MROWS * RANK * 4)
#define WS_KVB  (WS_CUR + (size_t)OUT_DIM * CSTRIDE * 4)

__device__ inline uint4 pack8(float4 a, float4 b) {
    union { __hip_bfloat16 h[8]; uint4 u; } w;
    w.h[0] = __float2bfloat16(a.x); w.h[1] = __float2bfloat16(a.y);
    w.h[2] = __float2bfloat16(a.z); w.h[3] = __float2bfloat16(a.w);
    w.h[4] = __float2bfloat16(b.x); w.h[5] = __float2bfloat16(b.y);
    w.h[6] = __float2bfloat16(b.z); w.h[7] = __float2bfloat16(b.w);
    return w.u;
}

__device__ inline float bfbits(uint32_t lo16) {
    union { uint32_t u; float f; } w; w.u = lo16 << 16; return w.f;
}

__device__ inline void fma8(float* acc, uint4 u, float v) {
    acc[0] += v * bfbits(u.x & 0xffffu);
    acc[1] += v * bfbits(u.x >> 16);
    acc[2] += v * bfbits(u.y & 0xffffu);
    acc[3] += v * bfbits(u.y >> 16);
    acc[4] += v * bfbits(u.z & 0xffffu);
    acc[5] += v * bfbits(u.z >> 16);
    acc[6] += v * bfbits(u.w & 0xffffu);
    acc[7] += v * bfbits(u.w >> 16);
}

// ---------------------------------------------------------------------------
// prep: sections by bid
//   [0,512)     x -> xT : 64x64 tile transpose, float4 reads / uint2 stores;
//               each block also zeroes 256 floats of t
//   [512,768)   Vhb gather (512 subvecs/block, 2/thread)
//   [768,1024)  Usb gather (*S); every block zeroes 256 cursor ints
//               (256 blocks x 256 = 65536 = OUT*CSTRIDE)
// ---------------------------------------------------------------------------
__global__ __launch_bounds__(256) void prep_kernel(
    const float* __restrict__ x,
    const int*   __restrict__ uidx, const float* __restrict__ ucode,
    const float* __restrict__ S,
    const int*   __restrict__ vidx, const float* __restrict__ vcode,
    __hip_bfloat16* __restrict__ Vhb, __hip_bfloat16* __restrict__ Usb,
    __hip_bfloat16* __restrict__ xT,
    int* __restrict__ cursor, float* __restrict__ tbuf)
{
    const int bid = blockIdx.x;
    const int t   = threadIdx.x;

    if (bid < 512) {
        __shared__ float tile[64][65];
        const int i0 = (bid >> 3) * 64;      // 64 i-tiles
        const int m0 = (bid & 7) * 64;       // 8 m-tiles
        const int rr = t >> 4, c4 = t & 15;
        #pragma unroll
        for (int p = 0; p < 4; p++) {
            int r = p * 16 + rr;
            float4 v = *(const float4*)(x + (size_t)(m0 + r) * IN_DIM + i0 + c4 * 4);
            tile[r][c4 * 4 + 0] = v.x;
            tile[r][c4 * 4 + 1] = v.y;
            tile[r][c4 * 4 + 2] = v.z;
            tile[r][c4 * 4 + 3] = v.w;
        }
        tbuf[bid * 256 + t] = 0.f;           // zero t (512*256 = |t|)
        __syncthreads();
        #pragma unroll
        for (int p = 0; p < 4; p++) {
            int i = p * 16 + rr;
            union { __hip_bfloat16 h[4]; uint2 u; } w;
            w.h[0] = __float2bfloat16(tile[c4 * 4 + 0][i]);
            w.h[1] = __float2bfloat16(tile[c4 * 4 + 1][i]);
            w.h[2] = __float2bfloat16(tile[c4 * 4 + 2][i]);
            w.h[3] = __float2bfloat16(tile[c4 * 4 + 3][i]);
            *(uint2*)(xT + (size_t)(i0 + i) * MROWS + m0 + c4 * 4) = w.u;
        }
    } else if (bid < 768) {
        int base = (bid - 512) * 512;
        #pragma unroll
        for (int q = 0; q < 2; q++) {
            int sv = base + q * 256 + t;
            int cb = vidx[sv];
            const float4* vc = (const float4*)(vcode + (size_t)cb * 8);
            *(uint4*)(Vhb + (size_t)sv * 8) = pack8(vc[0], vc[1]);
        }
    } else {
        int base = (bid - 768) * 512;
        #pragma unroll
        for (int q = 0; q < 2; q++) {
            int sv = base + q * 256 + t;
            int cb = uidx[sv];
            int r0 = (sv & 31) * 8;
            const float4* uc = (const float4*)(ucode + (size_t)cb * 8);
            const float4* sp = (const float4*)(S + r0);
            float4 a = uc[0], b = uc[1], sa = sp[0], sb = sp[1];
            a.x *= sa.x; a.y *= sa.y; a.z *= sa.z; a.w *= sa.w;
            b.x *= sb.x; b.y *= sb.y; b.z *= sb.z; b.w *= sb.w;
            *(uint4*)(Usb + (size_t)sv * 8) = pack8(a, b);
        }
        cursor[(bid - 768) * 256 + t] = 0;   // 256*256 = 65536 = OUT*CSTRIDE
    }
}

// ---------------------------------------------------------------------------
// scatter + gemm1 fused (both depend only on prep; independent outputs).
//   blocks [0,1024):    scatter residuals into CONTIGUOUS per-row buckets;
//     cursors line-padded (cursor[o*16]) -> 64 atomics per cache line
//     (vs 1024 unbanked / 256 banked). Buckets stay contiguous for phase B.
//   blocks [1024,1280): gemm1 MFMA, split-K=8, atomicAdd into t.
// ---------------------------------------------------------------------------
__global__ __launch_bounds__(256) void scatter_gemm1_kernel(
    const int* __restrict__ ridx, const float* __restrict__ rval,
    int* __restrict__ cursor, int2* __restrict__ kvb,
    const float* __restrict__ x,
    const __hip_bfloat16* __restrict__ Vhb,
    float* __restrict__ tbuf)
{
    if (blockIdx.x < 1024) {
        int k = blockIdx.x * 256 + threadIdx.x;
        int idx = ridx[k];
        int o = idx >> 12, i = idx & 4095;
        int pos = atomicAdd(&cursor[o * CSTRIDE], 1);
        if (pos < BCAP)                    // overflow ~1e-12 for this distribution
            kvb[(size_t)o * BCAP + pos] = make_int2(i, __float_as_int(rval[k]));
        return;
    }

    // ---- gemm1: t[512,256] += bf16(x) @ Vhb^T. split-K=8, BK=64, 8 steps ----
    __shared__ __align__(16) __hip_bfloat16 As[64][72];   // pitch 72: 2-way banks
    __shared__ __align__(16) __hip_bfloat16 Bs[64][72];

    const int bid = blockIdx.x - 1024;           // [0,256)
    const int ks = bid & 7, nb = (bid >> 3) & 3, mb = bid >> 5;
    const int m0 = mb * 64, n0 = nb * 64, kbase = ks * 512;
    const int t = threadIdx.x;
    const int lane = t & 63, wave = t >> 6;
    const int wm = wave >> 1, wn = wave & 1;
    const int l15 = lane & 15, l4 = lane >> 4;
    const int srow = t >> 2, sg = t & 3;

    f32x4 acc[2][2];
    #pragma unroll
    for (int i = 0; i < 2; i++)
        #pragma unroll
        for (int j = 0; j < 2; j++) acc[i][j] = (f32x4){0.f, 0.f, 0.f, 0.f};

    for (int s = 0; s < 8; s++) {
        int k0 = kbase + s * 64;
        const float* xp = x + (size_t)(m0 + srow) * IN_DIM + k0 + sg * 16;
        *(uint4*)&As[srow][sg * 16] =
            pack8(*(const float4*)xp, *(const float4*)(xp + 4));
        *(uint4*)&As[srow][sg * 16 + 8] =
            pack8(*(const float4*)(xp + 8), *(const float4*)(xp + 12));
        const __hip_bfloat16* bp = Vhb + (size_t)(n0 + srow) * IN_DIM + k0 + sg * 16;
        *(uint4*)&Bs[srow][sg * 16]     = *(const uint4*)bp;
        *(uint4*)&Bs[srow][sg * 16 + 8] = *(const uint4*)(bp + 8);
        __syncthreads();
        #pragma unroll
        for (int kk = 0; kk < 2; kk++) {
            bf16x8 a[2], b[2];
            #pragma unroll
            for (int i = 0; i < 2; i++)
                a[i] = *(const bf16x8*)&As[wm * 32 + i * 16 + l15][kk * 32 + l4 * 8];
            #pragma unroll
            for (int j = 0; j < 2; j++)
                b[j] = *(const bf16x8*)&Bs[wn * 32 + j * 16 + l15][kk * 32 + l4 * 8];
            #pragma unroll
            for (int i = 0; i < 2; i++)
                #pragma unroll
                for (int j = 0; j < 2; j++)
                    acc[i][j] = __builtin_amdgcn_mfma_f32_16x16x32_bf16(
                        a[i], b[j], acc[i][j], 0, 0, 0);
        }
        __syncthreads();
    }

    #pragma unroll
    for (int i = 0; i < 2; i++)
        #pragma unroll
        for (int j = 0; j < 2; j++)
            #pragma unroll
            for (int q = 0; q < 4; q++) {
                int row = m0 + wm * 32 + i * 16 + l4 * 4 + q;
                int col = n0 + wn * 32 + j * 16 + l15;
                atomicAdd(&tbuf[row * RANK + col], acc[i][j][q]);
            }
}

// ---------------------------------------------------------------------------
// GEMM2 + sparse fused: out[m][o] = (t @ Usb^T)[m][o] + residual[m][o].
// 32m x 64o tiles, grid 1024, XCD-affinity swizzle (mb = bid & 15) -> xT
// L2-resident per XCD (R13: -10us confirmed).
// Phase B: ONE contiguous ~64-entry stream per row (R13-proven; banked
// segments cost ~20us — reverted), 8-deep unroll, entries loaded as int4
// pairs (2 entries per 16B load).
// ---------------------------------------------------------------------------
__global__ __launch_bounds__(256) void gemm2_sparse_kernel(
    const float* __restrict__ tbuf,
    const __hip_bfloat16* __restrict__ Usb,
    const int* __restrict__ cursor,
    const int2* __restrict__ kvb,
    const __hip_bfloat16* __restrict__ xT,
    float* __restrict__ out)
{
    __shared__ __align__(16) char smem[14080];
    typedef __hip_bfloat16 bfrowA[72];
    typedef __hip_bfloat16 bfrowB[72];
    bfrowA* As = (bfrowA*)smem;                    //  32x72x2 = 4608 B
    bfrowB* Bs = (bfrowB*)(smem + 4608);           //  64x72x2 = 9216 B
    float (*sacc)[33] = (float(*)[33])smem;        //  64x33x4 = 8448 B (reused)

    const int bid = blockIdx.x;
    const int mb = bid & 15, nb = bid >> 4;        // XCD-affinity mapping
    const int m0 = mb * 32, n0 = nb * 64;
    const int t = threadIdx.x;
    const int lane = t & 63, wave = t >> 6;
    const int wm = wave >> 1, wn = wave & 1;
    const int l15 = lane & 15, l4 = lane >> 4;

    f32x4 acc[2];
    acc[0] = (f32x4){0.f, 0.f, 0.f, 0.f};
    acc[1] = (f32x4){0.f, 0.f, 0.f, 0.f};

    // ---- Phase A: dense MFMA ----
    {
        const int sa_row = t >> 3, sa_g = t & 7;   // A: 32 rows x 8 chunks of 8
        const int sb_row = t >> 2, sb_g = t & 3;   // B: 64 rows x 4 chunks of 16
        for (int s = 0; s < 4; s++) {
            int k0 = s * 64;
            const float* tp = tbuf + (size_t)(m0 + sa_row) * RANK + k0 + sa_g * 8;
            *(uint4*)&As[sa_row][sa_g * 8] =
                pack8(*(const float4*)tp, *(const float4*)(tp + 4));
            const __hip_bfloat16* bp =
                Usb + (size_t)(n0 + sb_row) * RANK + k0 + sb_g * 16;
            *(uint4*)&Bs[sb_row][sb_g * 16]     = *(const uint4*)bp;
            *(uint4*)&Bs[sb_row][sb_g * 16 + 8] = *(const uint4*)(bp + 8);
            __syncthreads();
            #pragma unroll
            for (int kk = 0; kk < 2; kk++) {
                bf16x8 a, b[2];
                a = *(const bf16x8*)&As[wm * 16 + l15][kk * 32 + l4 * 8];
                #pragma unroll
                for (int j = 0; j < 2; j++)
                    b[j] = *(const bf16x8*)&Bs[wn * 32 + j * 16 + l15][kk * 32 + l4 * 8];
                #pragma unroll
                for (int j = 0; j < 2; j++)
                    acc[j] = __builtin_amdgcn_mfma_f32_16x16x32_bf16(
                        a, b[j], acc[j], 0, 0, 0);
            }
            __syncthreads();
        }
    }

    // ---- Phase B: residual into sacc (contiguous stream, 8-deep, int4 pairs) ----
    {
        const int orel = t >> 2;              // o-row within tile (64)
        const int ms   = t & 3;               // 8-m slice (32m / 4)
        const int o    = n0 + orel;
        int cnt = cursor[o * CSTRIDE]; cnt = cnt < BCAP ? cnt : BCAP;
        const int2* kp  = kvb + (size_t)o * BCAP;
        const int4* kp4 = (const int4*)kp;    // row base 1KB-aligned
        const __hip_bfloat16* xm = xT + m0 + ms * 8;

        float r[8];
        #pragma unroll
        for (int j = 0; j < 8; j++) r[j] = 0.f;

        int k = 0;
        for (; k + 8 <= cnt; k += 8) {
            int4 e0 = kp4[(k >> 1) + 0], e1 = kp4[(k >> 1) + 1];
            int4 e2 = kp4[(k >> 1) + 2], e3 = kp4[(k >> 1) + 3];
            uint4 u0 = *(const uint4*)(xm + (size_t)e0.x * MROWS);
            uint4 u1 = *(const uint4*)(xm + (size_t)e0.z * MROWS);
            uint4 u2 = *(const uint4*)(xm + (size_t)e1.x * MROWS);
            uint4 u3 = *(const uint4*)(xm + (size_t)e1.z * MROWS);
            uint4 u4 = *(const uint4*)(xm + (size_t)e2.x * MROWS);
            uint4 u5 = *(const uint4*)(xm + (size_t)e2.z * MROWS);
            uint4 u6 = *(const uint4*)(xm + (size_t)e3.x * MROWS);
            uint4 u7 = *(const uint4*)(xm + (size_t)e3.z * MROWS);
            fma8(r, u0, __int_as_float(e0.y));
            fma8(r, u1, __int_as_float(e0.w));
            fma8(r, u2, __int_as_float(e1.y));
            fma8(r, u3, __int_as_float(e1.w));
            fma8(r, u4, __int_as_float(e2.y));
            fma8(r, u5, __int_as_float(e2.w));
            fma8(r, u6, __int_as_float(e3.y));
            fma8(r, u7, __int_as_float(e3.w));
        }
        if (k + 4 <= cnt) {
            int4 e0 = kp4[(k >> 1) + 0], e1 = kp4[(k >> 1) + 1];
            uint4 u0 = *(const uint4*)(xm + (size_t)e0.x * MROWS);
            uint4 u1 = *(const uint4*)(xm + (size_t)e0.z * MROWS);
            uint4 u2 = *(const uint4*)(xm + (size_t)e1.x * MROWS);
            uint4 u3 = *(const uint4*)(xm + (size_t)e1.z * MROWS);
            fma8(r, u0, __int_as_float(e0.y));
            fma8(r, u1, __int_as_float(e0.w));
            fma8(r, u2, __int_as_float(e1.y));
            fma8(r, u3, __int_as_float(e1.w));
            k += 4;
        }
        for (; k < cnt; k++) {
            int2 e = kp[k];
            uint4 u = *(const uint4*)(xm + (size_t)e.x * MROWS);
            fma8(r, u, __int_as_float(e.y));
        }

        *(float4*)&sacc[orel][ms * 8]     = make_float4(r[0], r[1], r[2], r[3]);
        *(float4*)&sacc[orel][ms * 8 + 4] = make_float4(r[4], r[5], r[6], r[7]);
    }
    __syncthreads();

    // ---- Phase C: epilogue (dense + sparse, single write) ----
    #pragma unroll
    for (int j = 0; j < 2; j++)
        #pragma unroll
        for (int q = 0; q < 4; q++) {
            int rrel = wm * 16 + l4 * 4 + q;        // m within tile (32)
            int crel = wn * 32 + j * 16 + l15;      // o within tile (64)
            out[(size_t)(m0 + rrel) * OUT_DIM + n0 + crel] =
                acc[j][q] + sacc[crel][rrel];
        }
}

// ---------------------------------------------------------------------------
extern "C" void kernel_launch(void* const* d_in, const int* in_sizes, int n_in,
                              void* d_out, int out_size, void* d_ws, size_t ws_size,
                              hipStream_t stream)
{
    const float* x    = (const float*)d_in[0];
    const int*   uidx = (const int*)  d_in[1];
    const float* ucb  = (const float*)d_in[2];
    const float* S    = (const float*)d_in[3];
    const int*   vidx = (const int*)  d_in[4];
    const float* vcb  = (const float*)d_in[5];
    const int*   ridx = (const int*)  d_in[6];
    const float* rval = (const float*)d_in[7];
    float* out = (float*)d_out;

    char* ws = (char*)d_ws;
    __hip_bfloat16* Vhb  = (__hip_bfloat16*)(ws + WS_VHB);
    __hip_bfloat16* Usb  = (__hip_bfloat16*)(ws + WS_USB);
    __hip_bfloat16* xT   = (__hip_bfloat16*)(ws + WS_XT);
    float*          tbuf = (float*)(ws + WS_T);
    int*            cur  = (int*)(ws + WS_CUR);
    int2*           kvb  = (int2*)(ws + WS_KVB);

    prep_kernel<<<dim3(1024), dim3(256), 0, stream>>>(
        x, uidx, ucb, S, vidx, vcb, Vhb, Usb, xT, cur, tbuf);

    scatter_gemm1_kernel<<<dim3(1280), dim3(256), 0, stream>>>(
        ridx, rval, cur, kvb, x, Vhb, tbuf);

    gemm2_sparse_kernel<<<dim3(1024), dim3(256), 0, stream>>>(
        tbuf, Usb, cur, kvb, xT, out);
}